// Round 1
// baseline (342.430 us; speedup 1.0000x reference)
//
#include <hip/hip_runtime.h>

typedef __bf16 bf16;
typedef __bf16 bf16x8 __attribute__((ext_vector_type(8)));
typedef __bf16 bf16x4 __attribute__((ext_vector_type(4)));
typedef float f32x4 __attribute__((ext_vector_type(4)));

#define N_DIM 196
#define C_DIM 768
#define B_DIM 256
#define KSTEPS 7           // 7*32 = 224 padded contraction length
#define MT1 14             // GEMM1 M-tiles (k-dim padded to 224)
#define MT2 13             // GEMM2 M-tiles (n-dim padded to 208 >= 196)
#define CT 64              // channels per block
#define LPITCH 232         // LDS pitch in bf16 elems (mult of 8 for b128 align; 116 dwords -> 2-way bank alias = free)

#define D2F_ELEMS (MT1 * KSTEPS * 512)
#define EF_ELEMS  (MT2 * KSTEPS * 512)

// Precompute DCT matrices in MFMA A-fragment lane order:
//   frag idx = ((mt*KSTEPS + ks)*64 + lane)*8 + j
//   A[row = mt*16 + (lane&15)][col = ks*32 + (lane>>4)*8 + j]
__global__ void init_mats(bf16* __restrict__ d2f, bf16* __restrict__ ef) {
    int idx = blockIdx.x * 256 + threadIdx.x;
    const float PI = 3.14159265358979323846f;
    if (idx < D2F_ELEMS) {
        int j    = idx & 7;
        int lane = (idx >> 3) & 63;
        int rest = idx >> 9;
        int ks = rest % KSTEPS;
        int mt = rest / KSTEPS;
        int row = mt * 16 + (lane & 15);         // output freq k
        int col = ks * 32 + (lane >> 4) * 8 + j; // spatial m
        float v = 0.0f;
        if (row < N_DIM && col < N_DIM) {
            // D2[k,m] = 2*cos(pi*(2m+1)*k/(2N)); reduce phase mod 2*pi exactly in ints
            int t = ((2 * col + 1) * row) % (4 * N_DIM);
            v = 2.0f * cosf(PI * (float)t / (float)(2 * N_DIM));
        }
        d2f[idx] = (bf16)v;
    } else {
        int e = idx - D2F_ELEMS;
        if (e < EF_ELEMS) {
            int j    = e & 7;
            int lane = (e >> 3) & 63;
            int rest = e >> 9;
            int ks = rest % KSTEPS;
            int mt = rest / KSTEPS;
            int row = mt * 16 + (lane & 15);         // output n
            int col = ks * 32 + (lane >> 4) * 8 + j; // freq k
            float v = 0.0f;
            if (row < N_DIM && col < N_DIM) {
                if (col == 0) {
                    v = 1.0f / (float)(2 * N_DIM);   // E[n,0] = 1/(2N)
                } else {
                    int t = ((2 * row + 1) * col) % (4 * N_DIM);
                    v = cosf(PI * (float)t / (float)(2 * N_DIM)) / (float)N_DIM;
                }
            }
            ef[e] = (bf16)v;
        }
    }
}

// One block = one batch b x 64-channel tile. Fused: T1 = D2@x_tile (MFMA),
// epilogue *w -> bf16 back into same LDS, y = E@T1w (MFMA), store fp32.
__global__ __launch_bounds__(256) void dct_fused(
        const float* __restrict__ x, const float* __restrict__ wgt,
        const bf16* __restrict__ d2f, const bf16* __restrict__ ef,
        float* __restrict__ out) {
    __shared__ bf16 lds[CT * LPITCH];   // 29,696 B

    const int b  = blockIdx.y;
    const int c0 = blockIdx.x * CT;
    const int t  = threadIdx.x;
    const int wave = t >> 6;
    const int lane = t & 63;
    const int ln15 = lane & 15;
    const int q    = lane >> 4;         // quad 0..3

    // ---- stage x[b, :, c0:c0+64] -> lds[c][m] (bf16), zero-pad m in [196,224)
    {
        int cj   = (t & 15) * 4;        // channel offset within tile
        int mrow = t >> 4;              // 0..15
        for (int i = 0; i < MT1; ++i) {
            int m = i * 16 + mrow;      // 0..223
            float4 v = make_float4(0.f, 0.f, 0.f, 0.f);
            if (m < N_DIM)
                v = *(const float4*)(x + ((size_t)b * N_DIM + m) * C_DIM + c0 + cj);
            lds[(cj + 0) * LPITCH + m] = (bf16)v.x;
            lds[(cj + 1) * LPITCH + m] = (bf16)v.y;
            lds[(cj + 2) * LPITCH + m] = (bf16)v.z;
            lds[(cj + 3) * LPITCH + m] = (bf16)v.w;
        }
    }
    __syncthreads();

    // ---- GEMM1: T1[k, c] = sum_m D2[k,m] * x[m,c]
    f32x4 acc[4][4] = {};
    for (int ks = 0; ks < KSTEPS; ++ks) {
        bf16x8 bfr[4];
#pragma unroll
        for (int ct = 0; ct < 4; ++ct)
            bfr[ct] = *(const bf16x8*)(lds + (ct * 16 + ln15) * LPITCH + ks * 32 + q * 8);
#pragma unroll
        for (int ml = 0; ml < 4; ++ml) {
            int mt = wave + 4 * ml;
            if (mt < MT1) {
                bf16x8 afr = *(const bf16x8*)(d2f + ((size_t)(mt * KSTEPS + ks) * 64 + lane) * 8);
#pragma unroll
                for (int ct = 0; ct < 4; ++ct)
                    acc[ml][ct] = __builtin_amdgcn_mfma_f32_16x16x32_bf16(afr, bfr[ct], acc[ml][ct], 0, 0, 0);
            }
        }
    }
    __syncthreads();

    // ---- epilogue: T1w[k,c] = T1[k,c]*w[c,k] -> bf16, stored to lds[c][k]
#pragma unroll
    for (int ml = 0; ml < 4; ++ml) {
        int mt = wave + 4 * ml;
        if (mt >= MT1) continue;
        int kb = mt * 16 + q * 4;       // 4 consecutive k (D rows = quad*4+reg)
#pragma unroll
        for (int ct = 0; ct < 4; ++ct) {
            int cc = ct * 16 + ln15;
            float4 wv = make_float4(0.f, 0.f, 0.f, 0.f);
            if (kb < N_DIM)             // kb mult of 4, 196 mult of 4 -> kb+3 < 196
                wv = *(const float4*)(wgt + (size_t)(c0 + cc) * N_DIM + kb);
            bf16x4 pv;
            pv[0] = (bf16)(acc[ml][ct][0] * wv.x);
            pv[1] = (bf16)(acc[ml][ct][1] * wv.y);
            pv[2] = (bf16)(acc[ml][ct][2] * wv.z);
            pv[3] = (bf16)(acc[ml][ct][3] * wv.w);
            *(bf16x4*)(lds + cc * LPITCH + kb) = pv;
        }
    }
    __syncthreads();

    // ---- GEMM2: y[n, c] = sum_k E[n,k] * T1w[k,c]
    f32x4 acc2[4][4] = {};
    for (int ks = 0; ks < KSTEPS; ++ks) {
        bf16x8 bfr[4];
#pragma unroll
        for (int ct = 0; ct < 4; ++ct)
            bfr[ct] = *(const bf16x8*)(lds + (ct * 16 + ln15) * LPITCH + ks * 32 + q * 8);
#pragma unroll
        for (int ml = 0; ml < 4; ++ml) {
            int mt = wave + 4 * ml;
            if (mt < MT2) {
                bf16x8 afr = *(const bf16x8*)(ef + ((size_t)(mt * KSTEPS + ks) * 64 + lane) * 8);
#pragma unroll
                for (int ct = 0; ct < 4; ++ct)
                    acc2[ml][ct] = __builtin_amdgcn_mfma_f32_16x16x32_bf16(afr, bfr[ct], acc2[ml][ct], 0, 0, 0);
            }
        }
    }

    // ---- store y[b, n, c] fp32 (coalesced 16-lane rows)
#pragma unroll
    for (int ml = 0; ml < 4; ++ml) {
        int mt = wave + 4 * ml;
        if (mt >= MT2) continue;
#pragma unroll
        for (int ct = 0; ct < 4; ++ct) {
            int cc = ct * 16 + ln15;
#pragma unroll
            for (int r = 0; r < 4; ++r) {
                int n = mt * 16 + q * 4 + r;
                if (n < N_DIM)
                    out[((size_t)b * N_DIM + n) * C_DIM + c0 + cc] = acc2[ml][ct][r];
            }
        }
    }
}

extern "C" void kernel_launch(void* const* d_in, const int* in_sizes, int n_in,
                              void* d_out, int out_size, void* d_ws, size_t ws_size,
                              hipStream_t stream) {
    const float* x   = (const float*)d_in[0];   // [256,196,768] fp32
    const float* wgt = (const float*)d_in[1];   // [768,196] fp32
    float* out = (float*)d_out;                 // [256,196,768] fp32

    bf16* d2f = (bf16*)d_ws;                    // 100,352 B
    bf16* ef  = d2f + D2F_ELEMS;                // 93,184 B  (total ~194 KB of ws)

    int tot = D2F_ELEMS + EF_ELEMS;
    init_mats<<<(tot + 255) / 256, 256, 0, stream>>>(d2f, ef);

    dim3 grid(C_DIM / CT, B_DIM);               // 12 x 256 = 3072 blocks
    dct_fused<<<grid, 256, 0, stream>>>(x, wgt, d2f, ef, out);
}